// Round 2
// baseline (209.925 us; speedup 1.0000x reference)
//
#include <hip/hip_runtime.h>
#include <stdint.h>

typedef __attribute__((ext_vector_type(8))) short short8v;
typedef __attribute__((ext_vector_type(4))) float float4v;

__device__ __forceinline__ unsigned short f32_to_bf16(float f) {
    union { float f; uint32_t u; } v; v.f = f;
    uint32_t u = v.u;
    u += 0x7FFFu + ((u >> 16) & 1u);
    return (unsigned short)(u >> 16);
}

#define T_LEN 4096
#define C_DIM 1024
#define HSZ 64

// ---------------- kernel 0: W -> Wt (bf16, transposed [192][1024]) ----------------
__global__ void wt_kernel(const float* __restrict__ Wq, const float* __restrict__ Wk,
                          const float* __restrict__ Wv, unsigned short* __restrict__ Wt) {
    int tid = blockIdx.x * blockDim.x + threadIdx.x;   // 0 .. 3*65536-1
    int m   = tid >> 16;
    int rem = tid & 65535;
    int kk  = rem >> 6;
    int col = rem & 63;
    const float* W = (m == 0) ? Wq : ((m == 1) ? Wk : Wv);
    Wt[(size_t)m * 65536 + (size_t)col * 1024 + kk] = f32_to_bf16(W[(size_t)kk * 64 + col]);
}

// ---------------- kernel 1: fused QKV projection ----------------
#define XLD 1032   // 1024 + 8 pad (2064 B row stride: 16B-aligned, bank-spread)

__global__ __launch_bounds__(256) void qkv_kernel(
    const float* __restrict__ x, const unsigned short* __restrict__ Wt,
    unsigned short* __restrict__ qo, unsigned short* __restrict__ ko,
    unsigned short* __restrict__ vo)
{
    __shared__ __align__(16) unsigned short xs[16 * XLD];
    const int tid  = threadIdx.x;
    const int row0 = blockIdx.x * 16;

    // stage 16 x-rows (fp32 -> bf16), float4 coalesced reads, b64 LDS writes
    #pragma unroll
    for (int i = 0; i < 16; ++i) {
        int f   = i * 256 + tid;           // float4 index, 4096 total
        int row = f >> 8, c4 = f & 255;
        const float4 val = *((const float4*)x + (size_t)(row0 + row) * 256 + c4);
        union { unsigned short s[4]; uint64_t u; } pk;
        pk.s[0] = f32_to_bf16(val.x); pk.s[1] = f32_to_bf16(val.y);
        pk.s[2] = f32_to_bf16(val.z); pk.s[3] = f32_to_bf16(val.w);
        *(uint64_t*)(&xs[row * XLD + c4 * 4]) = pk.u;
    }
    __syncthreads();

    const int wave = tid >> 6, lane = tid & 63;
    const int g = lane >> 4, c = lane & 15;

    float4v acc0 = {0,0,0,0}, acc1 = {0,0,0,0}, acc2 = {0,0,0,0};
    #pragma unroll 4
    for (int ks = 0; ks < 32; ++ks) {
        const int koff = ks * 32 + g * 8;
        short8v a  = *(const short8v*)(&xs[c * XLD + koff]);
        short8v b0 = *(const short8v*)(&Wt[(size_t)((wave*3+0)*16 + c) * 1024 + koff]);
        short8v b1 = *(const short8v*)(&Wt[(size_t)((wave*3+1)*16 + c) * 1024 + koff]);
        short8v b2 = *(const short8v*)(&Wt[(size_t)((wave*3+2)*16 + c) * 1024 + koff]);
        acc0 = __builtin_amdgcn_mfma_f32_16x16x32_bf16(a, b0, acc0, 0, 0, 0);
        acc1 = __builtin_amdgcn_mfma_f32_16x16x32_bf16(a, b1, acc1, 0, 0, 0);
        acc2 = __builtin_amdgcn_mfma_f32_16x16x32_bf16(a, b2, acc2, 0, 0, 0);
    }

    float4v accs[3] = {acc0, acc1, acc2};
    #pragma unroll
    for (int t = 0; t < 3; ++t) {
        int ct = wave * 3 + t;
        int m = ct >> 2, hcol = (ct & 3) * 16 + c;
        unsigned short* dst = (m == 0) ? qo : ((m == 1) ? ko : vo);
        float sc = (m == 0) ? 0.125f : 1.0f;   // fold 1/sqrt(64) into q
        #pragma unroll
        for (int j = 0; j < 4; ++j)
            dst[(size_t)(row0 + g * 4 + j) * 64 + hcol] = f32_to_bf16(accs[t][j] * sc);
    }
}

// ---------------- kernel 2: causal flash attention ----------------
#define KLD 72   // 144 B stride: 16B-aligned b128 B-frag reads
#define VLD 66   // 132 B stride: stride_bytes % 8 == 4 -> scalar u16 reads spread banks
#define PLD 72

__global__ __launch_bounds__(128) void attn_kernel(
    const unsigned short* __restrict__ qi, const unsigned short* __restrict__ ki,
    const unsigned short* __restrict__ vi, float* __restrict__ out)
{
    __shared__ __align__(16) unsigned short Ks[64 * KLD];
    __shared__ __align__(16) unsigned short Vs[64 * VLD];
    __shared__ __align__(16) unsigned short Ps[2 * 16 * PLD];

    const int tid  = threadIdx.x;
    const int wave = tid >> 6, lane = tid & 63;
    const int g = lane >> 4, c = lane & 15;
    const int b = blockIdx.y;
    const int qb = 127 - (int)blockIdx.x;       // LPT: longest q-strips dispatched first
    const int rbase = qb * 32 + wave * 16;
    const size_t bo = (size_t)b * T_LEN * HSZ;

    // Q A-fragments, held in registers for the whole KV loop
    short8v qf0 = *(const short8v*)(qi + bo + (size_t)(rbase + c) * 64 +  0 + g * 8);
    short8v qf1 = *(const short8v*)(qi + bo + (size_t)(rbase + c) * 64 + 32 + g * 8);

    float4v acc[4];
    #pragma unroll
    for (int i2 = 0; i2 < 4; ++i2) acc[i2] = (float4v){0,0,0,0};
    float mrow[4] = {-3e38f, -3e38f, -3e38f, -3e38f};
    float lrow[4] = {0.f, 0.f, 0.f, 0.f};
    const int nt = (qb * 32 + 32 + 63) >> 6;
    unsigned short* Pw = &Ps[wave * 16 * PLD];

    for (int t = 0; t < nt; ++t) {
        const int s0 = t * 64;
        // stage K and V tiles (64x64 bf16 each)
        #pragma unroll
        for (int i = 0; i < 4; ++i) {
            int chunk = i * 128 + tid;            // 512 chunks of 8 bf16
            int s = chunk >> 3, d0 = (chunk & 7) * 8;
            const uint4 kk = *(const uint4*)(ki + bo + (size_t)(s0 + s) * 64 + d0);
            *(uint4*)(&Ks[s * KLD + d0]) = kk;
            const uint4 vv = *(const uint4*)(vi + bo + (size_t)(s0 + s) * 64 + d0);
            uint32_t* vp = (uint32_t*)(&Vs[s * VLD + d0]);  // 4B-aligned only
            vp[0] = vv.x; vp[1] = vv.y; vp[2] = vv.z; vp[3] = vv.w;
        }
        __syncthreads();

        // S = Q K^T  (per wave: 16 q-rows x 64 s-cols)
        // second K-slice of the 64-wide d-dim starts at element 32 (NOT 64)
        float4v sa[4];
        #pragma unroll
        for (int ct = 0; ct < 4; ++ct) {
            sa[ct] = (float4v){0,0,0,0};
            short8v b0 = *(const short8v*)(&Ks[(ct * 16 + c) * KLD +  0 + g * 8]);
            sa[ct] = __builtin_amdgcn_mfma_f32_16x16x32_bf16(qf0, b0, sa[ct], 0, 0, 0);
            short8v b1 = *(const short8v*)(&Ks[(ct * 16 + c) * KLD + 32 + g * 8]);
            sa[ct] = __builtin_amdgcn_mfma_f32_16x16x32_bf16(qf1, b1, sa[ct], 0, 0, 0);
        }

        // causal mask (only tiles that can violate)
        if (s0 + 63 > rbase) {
            #pragma unroll
            for (int ct = 0; ct < 4; ++ct)
                #pragma unroll
                for (int j = 0; j < 4; ++j)
                    if (s0 + ct * 16 + c > rbase + g * 4 + j) sa[ct][j] = -3e38f;
        }

        // online softmax; D-layout: row = g*4+j, col = ct*16+c (16-lane groups)
        #pragma unroll
        for (int j = 0; j < 4; ++j) {
            float mx = fmaxf(fmaxf(sa[0][j], sa[1][j]), fmaxf(sa[2][j], sa[3][j]));
            #pragma unroll
            for (int sh = 1; sh < 16; sh <<= 1) mx = fmaxf(mx, __shfl_xor(mx, sh, 64));
            const float nm = fmaxf(mrow[j], mx);
            const float al = __expf(mrow[j] - nm);
            mrow[j] = nm;
            float ps = 0.f;
            #pragma unroll
            for (int ct = 0; ct < 4; ++ct) {
                float p = __expf(sa[ct][j] - nm);
                sa[ct][j] = p;
                ps += p;
            }
            #pragma unroll
            for (int sh = 1; sh < 16; sh <<= 1) ps += __shfl_xor(ps, sh, 64);
            lrow[j] = lrow[j] * al + ps;
            #pragma unroll
            for (int ct = 0; ct < 4; ++ct) acc[ct][j] *= al;
        }

        // P (D-layout) -> per-wave LDS -> A-fragment layout
        #pragma unroll
        for (int ct = 0; ct < 4; ++ct)
            #pragma unroll
            for (int j = 0; j < 4; ++j)
                Pw[(g * 4 + j) * PLD + ct * 16 + c] = f32_to_bf16(sa[ct][j]);

        // second s-slice of the 64-wide P row starts at element 32 (NOT 64)
        short8v pa0 = *(const short8v*)(&Pw[c * PLD +  0 + g * 8]);
        short8v pa1 = *(const short8v*)(&Pw[c * PLD + 32 + g * 8]);

        // O += P V
        #pragma unroll
        for (int ks = 0; ks < 2; ++ks) {
            #pragma unroll
            for (int ct = 0; ct < 4; ++ct) {
                short8v vb;
                #pragma unroll
                for (int j = 0; j < 8; ++j)
                    vb[j] = (short)Vs[(ks * 32 + g * 8 + j) * VLD + ct * 16 + c];
                acc[ct] = __builtin_amdgcn_mfma_f32_16x16x32_bf16(ks == 0 ? pa0 : pa1, vb, acc[ct], 0, 0, 0);
            }
        }
        __syncthreads();
    }

    // epilogue: O / l
    #pragma unroll
    for (int ct = 0; ct < 4; ++ct)
        #pragma unroll
        for (int j = 0; j < 4; ++j)
            out[bo + (size_t)(rbase + g * 4 + j) * 64 + ct * 16 + c] = acc[ct][j] / lrow[j];
}

extern "C" void kernel_launch(void* const* d_in, const int* in_sizes, int n_in,
                              void* d_out, int out_size, void* d_ws, size_t ws_size,
                              hipStream_t stream) {
    const float* x  = (const float*)d_in[0];
    const float* Wq = (const float*)d_in[1];
    const float* Wk = (const float*)d_in[2];
    const float* Wv = (const float*)d_in[3];

    unsigned short* Wt = (unsigned short*)d_ws;                        // 3*64*1024*2 = 384 KiB
    unsigned short* q  = (unsigned short*)((char*)d_ws + (size_t)3 * 65536 * 2);
    unsigned short* k  = q + (size_t)4 * T_LEN * HSZ;
    unsigned short* v  = k + (size_t)4 * T_LEN * HSZ;
    float* out = (float*)d_out;

    hipLaunchKernelGGL(wt_kernel,  dim3(768),     dim3(256), 0, stream, Wq, Wk, Wv, Wt);
    hipLaunchKernelGGL(qkv_kernel, dim3(1024),    dim3(256), 0, stream, x, Wt, q, k, v);
    hipLaunchKernelGGL(attn_kernel, dim3(128, 4), dim3(128), 0, stream, q, k, v, out);
}